// Round 4
// baseline (848.081 us; speedup 1.0000x reference)
//
#include <hip/hip_runtime.h>

#define BB 256
#define C0 64
#define LL 2048
#define PP 192
#define GG 48
#define CO 112
#define PBK 24   // PP/8

typedef float f32x4 __attribute__((ext_vector_type(4)));
typedef __bf16 bf16x8 __attribute__((ext_vector_type(8)));

// ws layout:
//   [0, OUT1_BYTES)          out1 bf16 [b][pb][l][8]   201,326,592 B
//   [OUT1_BYTES, +H_BYTES)   h f32 [b][g][l]           100,663,296 B
//   zr floats (memset 0 every launch):
//     bn1s [8][64]   @0       bn1q [8][64]   @512
//     bn2s [32][192] @1024    bn2q [32][192] @7168
//     norms2 [256*48] @13312  sim [256*2304] @25600 .. 615424
//   par floats @zr+615424: scale1[64] shift1[64] scale2[192] shift2[192]
//   W1p bf16 [192][64]; W2p bf16 [3][48][192]
static constexpr size_t OUT1_BYTES = (size_t)BB * PP * LL * 2;
static constexpr size_t H_BYTES    = (size_t)BB * GG * LL * 4;
static constexpr int ZR_FLOATS = 615424;
static constexpr int ZO_BN1S = 0, ZO_BN1Q = 512, ZO_BN2S = 1024, ZO_BN2Q = 7168;
static constexpr int ZO_NRM = 13312, ZO_SIM = 25600;

__device__ __forceinline__ float bflo(unsigned w) { return __uint_as_float(w << 16); }
__device__ __forceinline__ float bfhi(unsigned w) { return __uint_as_float(w & 0xffff0000u); }
__device__ __forceinline__ unsigned pk2bf(float a, float b) {
    unsigned r;
    asm("v_cvt_pk_bf16_f32 %0, %1, %2" : "=v"(r) : "v"(a), "v"(b));  // lo=a, hi=b, RNE
    return r;
}
__device__ __forceinline__ unsigned short f2bf(float f) {
    unsigned u = __float_as_uint(f); u += 0x7fffu + ((u >> 16) & 1u);
    return (unsigned short)(u >> 16);
}
// activate a bf16 pair (packed in w) with per-element scale/shift, repack to bf16 pair
__device__ __forceinline__ unsigned act2(unsigned w, float s0, float s1, float h0, float h1) {
    float y0 = fmaxf(fmaf(s0, bflo(w), h0), 0.f);
    float y1 = fmaxf(fmaf(s1, bfhi(w), h1), 0.f);
    return pk2bf(y0, y1);
}

// pack W1 -> bf16 [192][64]; W2 [48][192][3] -> bf16 [tap][48][192]
__global__ void kp_pack(const float* __restrict__ W1, const float* __restrict__ W2,
                        unsigned short* __restrict__ W1p, unsigned short* __restrict__ W2p) {
    int i = blockIdx.x * 256 + threadIdx.x;
    if (i < PP * C0) W1p[i] = f2bf(W1[i]);
    if (i < 3 * GG * PP) {
        int tap = i / (GG * PP), r = i % (GG * PP);
        int g = r / PP, p = r % PP;
        W2p[i] = f2bf(W2[(g * PP + p) * 3 + tap]);
    }
}

// K1: BN1 stats + copy x -> out[:,0:64,:]. Fully coalesced 1KB wave loads.
__global__ __launch_bounds__(256) void k1_stats_copy(
        const float* __restrict__ x, float* __restrict__ out,
        float* __restrict__ bn1s, float* __restrict__ bn1q) {
    int b = blockIdx.x, lc = blockIdx.y, t = threadIdx.x;
    int lane = t & 63, w = t >> 6;
    const float4* x4 = (const float4*)x;
    float4* o4 = (float4*)out;
    float s[16], q[16];
    #pragma unroll
    for (int it = 0; it < 16; ++it) { s[it] = 0.f; q[it] = 0.f; }
    #pragma unroll
    for (int it = 0; it < 16; ++it) {
        int c = w + 4 * it;                       // wave-uniform channel
        #pragma unroll
        for (int j = 0; j < 2; ++j) {
            size_t idx = (size_t)(b * C0 + c) * 512 + lc * 128 + j * 64 + lane;
            float4 v = x4[idx];
            o4[(size_t)(b * CO + c) * 512 + lc * 128 + j * 64 + lane] = v;
            s[it] += v.x + v.y + v.z + v.w;
            q[it] += v.x * v.x + v.y * v.y + v.z * v.z + v.w * v.w;
        }
    }
    #pragma unroll
    for (int it = 0; it < 16; ++it) {
        float a = s[it], d = q[it];
        #pragma unroll
        for (int m = 1; m < 64; m <<= 1) { a += __shfl_xor(a, m); d += __shfl_xor(d, m); }
        if (lane == 0) {
            int c = w + 4 * it;
            int sp = (b * 4 + lc) & 7;
            atomicAdd(&bn1s[sp * C0 + c], a);
            atomicAdd(&bn1q[sp * C0 + c], d);
        }
    }
}

// finalize BN from spread partial sums
__global__ void k_bn_final(const float* __restrict__ ss, const float* __restrict__ qq,
                           const float* __restrict__ gamma, const float* __restrict__ beta,
                           float* __restrict__ scale, float* __restrict__ shift,
                           int C, int nspread, float invN) {
    int c = threadIdx.x;
    if (c < C) {
        float s = 0.f, q = 0.f;
        for (int k = 0; k < nspread; ++k) { s += ss[k * C + c]; q += qq[k * C + c]; }
        float mean = s * invN;
        float var  = q * invN - mean * mean;
        float r    = rsqrtf(var + 1e-5f);
        float sc   = gamma[c] * r;
        scale[c] = sc;
        shift[c] = beta[c] - mean * sc;
    }
}

// K2: out1 = conv1x1(relu(bn1(x))) via MFMA, reading x f32 directly.
// Also accumulates BN2 stats from the pre-rounding f32 accumulators (k3 eliminated).
__global__ __launch_bounds__(256) void k2_conv1(
        const float* __restrict__ x, const unsigned short* __restrict__ W1p,
        const float* __restrict__ par, unsigned short* __restrict__ out1,
        float* __restrict__ bn2s, float* __restrict__ bn2q) {
    int b = blockIdx.x, lt = blockIdx.y, t = threadIdx.x;
    int lane = t & 63;
    int w = __builtin_amdgcn_readfirstlane(t >> 6);
    int lm = lane & 15, lg = lane >> 4;
    union AF { uint4 q; bf16x8 v; };
    AF afr[3][2];
    #pragma unroll
    for (int gf = 0; gf < 3; ++gf)
        #pragma unroll
        for (int kc = 0; kc < 2; ++kc)
            afr[gf][kc].q = *(const uint4*)&W1p[(w * 48 + gf * 16 + lm) * C0 + kc * 32 + lg * 8];
    f32x4 acc[3][8];
    #pragma unroll
    for (int gf = 0; gf < 3; ++gf)
        #pragma unroll
        for (int lf = 0; lf < 8; ++lf) acc[gf][lf] = f32x4{0.f, 0.f, 0.f, 0.f};
    int l0 = lt * 128;
    #pragma unroll
    for (int kc = 0; kc < 2; ++kc) {
        int c0 = kc * 32 + lg * 8;
        float sc[8], sh[8];
        #pragma unroll
        for (int j = 0; j < 8; ++j) { sc[j] = par[c0 + j]; sh[j] = par[64 + c0 + j]; }
        #pragma unroll
        for (int lf = 0; lf < 8; ++lf) {
            int l = l0 + lf * 16 + lm;
            float yv[8];
            #pragma unroll
            for (int j = 0; j < 8; ++j)
                yv[j] = fmaxf(fmaf(sc[j], x[(size_t)(b * C0 + c0 + j) * LL + l], sh[j]), 0.f);
            union { uint4 q; bf16x8 v; } bf;
            bf.q.x = pk2bf(yv[0], yv[1]); bf.q.y = pk2bf(yv[2], yv[3]);
            bf.q.z = pk2bf(yv[4], yv[5]); bf.q.w = pk2bf(yv[6], yv[7]);
            #pragma unroll
            for (int gf = 0; gf < 3; ++gf)
                acc[gf][lf] = __builtin_amdgcn_mfma_f32_16x16x32_bf16(afr[gf][kc].v, bf.v, acc[gf][lf], 0, 0, 0);
        }
    }
    // store out1 (bf16) + accumulate BN2 stats from f32 values
    float s12[12], q12[12];
    #pragma unroll
    for (int i = 0; i < 12; ++i) { s12[i] = 0.f; q12[i] = 0.f; }
    #pragma unroll
    for (int gf = 0; gf < 3; ++gf) {
        int g0 = w * 48 + gf * 16 + lg * 4;
        size_t obase = ((size_t)b * PBK + (g0 >> 3)) * LL * 8 + (g0 & 7);
        #pragma unroll
        for (int lf = 0; lf < 8; ++lf) {
            int l = l0 + lf * 16 + lm;
            uint2 pk;
            pk.x = pk2bf(acc[gf][lf][0], acc[gf][lf][1]);
            pk.y = pk2bf(acc[gf][lf][2], acc[gf][lf][3]);
            *(uint2*)&out1[obase + (size_t)l * 8] = pk;
            #pragma unroll
            for (int r = 0; r < 4; ++r) {
                float v = acc[gf][lf][r];
                s12[gf * 4 + r] += v;
                q12[gf * 4 + r] = fmaf(v, v, q12[gf * 4 + r]);
            }
        }
    }
    int sp = (blockIdx.x * 16 + blockIdx.y) & 31;
    #pragma unroll
    for (int i = 0; i < 12; ++i) {
        float a = s12[i], d = q12[i];
        #pragma unroll
        for (int m = 1; m < 16; m <<= 1) { a += __shfl_xor(a, m); d += __shfl_xor(d, m); }
        if (lm == 0) {
            int g = w * 48 + (i >> 2) * 16 + lg * 4 + (i & 3);
            atomicAdd(&bn2s[sp * PP + g], a);
            atomicAdd(&bn2q[sp * PP + g], d);
        }
    }
}

// K4: h = conv3(relu(bn2(out1))) via MFMA with activated z staged ONCE in LDS.
// zl bf16 [24 pb][130 li][8 p]; li=0 is l0-1 (halo), li=129 is l0+128 (halo).
__global__ __launch_bounds__(256) void k4_conv2(
        const unsigned short* __restrict__ out1, const unsigned short* __restrict__ W2p,
        const float* __restrict__ par, float* __restrict__ h, float* __restrict__ norms2) {
    int b = blockIdx.x, lt = blockIdx.y, t = threadIdx.x;
    __shared__ unsigned short zl[PBK * 130 * 8];
    const float* sc2 = par + 128;
    const float* sh2 = par + 320;
    int l0 = lt * 128;
    // stage interior: 24 pb x 128 l
    #pragma unroll
    for (int j = 0; j < 12; ++j) {
        int f = j * 256 + t;
        int pb = f >> 7, fl = f & 127;
        uint4 qv = *(const uint4*)&out1[(((size_t)(b * PBK + pb)) * LL + l0 + fl) * 8];
        float4 sa = *(const float4*)&sc2[pb * 8];
        float4 sb = *(const float4*)&sc2[pb * 8 + 4];
        float4 ha = *(const float4*)&sh2[pb * 8];
        float4 hb = *(const float4*)&sh2[pb * 8 + 4];
        uint4 z;
        z.x = act2(qv.x, sa.x, sa.y, ha.x, ha.y);
        z.y = act2(qv.y, sa.z, sa.w, ha.z, ha.w);
        z.z = act2(qv.z, sb.x, sb.y, hb.x, hb.y);
        z.w = act2(qv.w, sb.z, sb.w, hb.z, hb.w);
        *(uint4*)&zl[(pb * 130 + 1 + fl) * 8] = z;
    }
    // stage halo: li = 0 (l0-1) and li = 129 (l0+128), zero outside [0,2048)
    if (t < 48) {
        int pb = t >> 1, side = t & 1;
        int li = side ? 129 : 0;
        int l = l0 - 1 + li;
        uint4 z = uint4{0u, 0u, 0u, 0u};
        if ((unsigned)l < (unsigned)LL) {
            uint4 qv = *(const uint4*)&out1[(((size_t)(b * PBK + pb)) * LL + l) * 8];
            float4 sa = *(const float4*)&sc2[pb * 8];
            float4 sb = *(const float4*)&sc2[pb * 8 + 4];
            float4 ha = *(const float4*)&sh2[pb * 8];
            float4 hb = *(const float4*)&sh2[pb * 8 + 4];
            z.x = act2(qv.x, sa.x, sa.y, ha.x, ha.y);
            z.y = act2(qv.y, sa.z, sa.w, ha.z, ha.w);
            z.z = act2(qv.z, sb.x, sb.y, hb.x, hb.y);
            z.w = act2(qv.w, sb.z, sb.w, hb.z, hb.w);
        }
        *(uint4*)&zl[(pb * 130 + li) * 8] = z;
    }
    __syncthreads();
    int lane = t & 63;
    int w = __builtin_amdgcn_readfirstlane(t >> 6);
    int lm = lane & 15, lg = lane >> 4;
    f32x4 acc[3][2];
    #pragma unroll
    for (int gf = 0; gf < 3; ++gf) { acc[gf][0] = f32x4{0.f,0.f,0.f,0.f}; acc[gf][1] = f32x4{0.f,0.f,0.f,0.f}; }
    for (int pc = 0; pc < 6; ++pc) {
        int pb = pc * 4 + lg;
        #pragma unroll
        for (int tap = 0; tap < 3; ++tap) {
            union AF { uint4 q; bf16x8 v; };
            AF afr[3];
            #pragma unroll
            for (int gf = 0; gf < 3; ++gf)
                afr[gf].q = *(const uint4*)&W2p[(tap * GG + gf * 16 + lm) * PP + pc * 32 + lg * 8];
            #pragma unroll
            for (int lf = 0; lf < 2; ++lf) {
                int li = w * 32 + lf * 16 + lm + tap;
                bf16x8 bv = *(const bf16x8*)&zl[(pb * 130 + li) * 8];
                #pragma unroll
                for (int gf = 0; gf < 3; ++gf)
                    acc[gf][lf] = __builtin_amdgcn_mfma_f32_16x16x32_bf16(afr[gf].v, bv, acc[gf][lf], 0, 0, 0);
            }
        }
    }
    int lb = l0 + w * 32;
    #pragma unroll
    for (int gf = 0; gf < 3; ++gf) {
        #pragma unroll
        for (int lf = 0; lf < 2; ++lf) {
            int l = lb + lf * 16 + lm;
            #pragma unroll
            for (int r = 0; r < 4; ++r) {
                int g = gf * 16 + lg * 4 + r;
                h[((size_t)(b * GG + g)) * LL + l] = acc[gf][lf][r];
            }
        }
        #pragma unroll
        for (int r = 0; r < 4; ++r) {
            float nv = acc[gf][0][r] * acc[gf][0][r] + acc[gf][1][r] * acc[gf][1][r];
            nv += __shfl_xor(nv, 1); nv += __shfl_xor(nv, 2);
            nv += __shfl_xor(nv, 4); nv += __shfl_xor(nv, 8);
            if (lm == 0) atomicAdd(&norms2[b * GG + gf * 16 + lg * 4 + r], nv);
        }
    }
}

// K6: raw Gram sim[b,c,d] = sum_l h[b,c,l]*h[b,d,l]
__global__ __launch_bounds__(256) void k6_gram(
        const float* __restrict__ h, float* __restrict__ sim) {
    int b = blockIdx.x, ch = blockIdx.y, t = threadIdx.x;
    __shared__ float hl[GG * 260];
    int tr = t >> 4, tc = t & 15;
    float s00 = 0, s01 = 0, s02 = 0, s10 = 0, s11 = 0, s12 = 0, s20 = 0, s21 = 0, s22 = 0;
    for (int sub = 0; sub < 2; ++sub) {
        __syncthreads();
        for (int j = 0; j < 12; ++j) {
            int f = j * 256 + t;
            int r = f >> 6, lq = f & 63;
            float4 v = ((const float4*)h)[(size_t)(b * GG + r) * 512 + ch * 128 + sub * 64 + lq];
            *(float4*)&hl[r * 260 + lq * 4] = v;
        }
        __syncthreads();
        for (int l4 = 0; l4 < 64; ++l4) {
            float4 r0 = *(const float4*)&hl[(3 * tr + 0) * 260 + l4 * 4];
            float4 r1 = *(const float4*)&hl[(3 * tr + 1) * 260 + l4 * 4];
            float4 r2 = *(const float4*)&hl[(3 * tr + 2) * 260 + l4 * 4];
            float4 c0 = *(const float4*)&hl[(3 * tc + 0) * 260 + l4 * 4];
            float4 c1 = *(const float4*)&hl[(3 * tc + 1) * 260 + l4 * 4];
            float4 c2 = *(const float4*)&hl[(3 * tc + 2) * 260 + l4 * 4];
            s00 += r0.x * c0.x + r0.y * c0.y + r0.z * c0.z + r0.w * c0.w;
            s01 += r0.x * c1.x + r0.y * c1.y + r0.z * c1.z + r0.w * c1.w;
            s02 += r0.x * c2.x + r0.y * c2.y + r0.z * c2.z + r0.w * c2.w;
            s10 += r1.x * c0.x + r1.y * c0.y + r1.z * c0.z + r1.w * c0.w;
            s11 += r1.x * c1.x + r1.y * c1.y + r1.z * c1.z + r1.w * c1.w;
            s12 += r1.x * c2.x + r1.y * c2.y + r1.z * c2.z + r1.w * c2.w;
            s20 += r2.x * c0.x + r2.y * c0.y + r2.z * c0.z + r2.w * c0.w;
            s21 += r2.x * c1.x + r2.y * c1.y + r2.z * c1.z + r2.w * c1.w;
            s22 += r2.x * c2.x + r2.y * c2.y + r2.z * c2.z + r2.w * c2.w;
        }
    }
    float* sb = &sim[(size_t)b * 2304];
    atomicAdd(&sb[(3 * tr + 0) * 48 + 3 * tc + 0], s00);
    atomicAdd(&sb[(3 * tr + 0) * 48 + 3 * tc + 1], s01);
    atomicAdd(&sb[(3 * tr + 0) * 48 + 3 * tc + 2], s02);
    atomicAdd(&sb[(3 * tr + 1) * 48 + 3 * tc + 0], s10);
    atomicAdd(&sb[(3 * tr + 1) * 48 + 3 * tc + 1], s11);
    atomicAdd(&sb[(3 * tr + 1) * 48 + 3 * tc + 2], s12);
    atomicAdd(&sb[(3 * tr + 2) * 48 + 3 * tc + 0], s20);
    atomicAdd(&sb[(3 * tr + 2) * 48 + 3 * tc + 1], s21);
    atomicAdd(&sb[(3 * tr + 2) * 48 + 3 * tc + 2], s22);
}

// K7: cosine-normalize, softmax, residual, PV -> out[:,64:112,:]
__global__ __launch_bounds__(256) void k7_softmax_pv(
        const float* __restrict__ h, const float* __restrict__ sim,
        const float* __restrict__ norms2, float* __restrict__ out) {
    int b = blockIdx.x, ch = blockIdx.y, t = threadIdx.x;
    __shared__ float att[GG][GG];
    __shared__ float nrm[GG];
    if (t < GG) nrm[t] = sqrtf(norms2[b * GG + t]);
    __syncthreads();
    if (t < GG) {
        int r = t;
        const float* sr = &sim[(size_t)b * 2304 + r * 48];
        float nr = nrm[r];
        float m = -1e30f;
        for (int d = 0; d < GG; ++d) {
            float v = sr[d] / fmaxf(nr * nrm[d], 1e-8f);
            att[r][d] = v;
            m = fmaxf(m, v);
        }
        float ssum = 0.f;
        for (int d = 0; d < GG; ++d) {
            float e = __expf(att[r][d] - m);
            att[r][d] = e;
            ssum += e;
        }
        float inv = 1.f / ssum;
        for (int d = 0; d < GG; ++d) att[r][d] *= inv;
        att[r][r] += 1.0f;
    }
    __syncthreads();
    int l = ch * 512 + t;
    float h0[GG], h1[GG];
    #pragma unroll
    for (int d = 0; d < GG; ++d) {
        h0[d] = h[(size_t)(b * GG + d) * LL + l];
        h1[d] = h[(size_t)(b * GG + d) * LL + l + 256];
    }
    for (int c = 0; c < GG; ++c) {
        float a0 = 0.f, a1 = 0.f;
        #pragma unroll
        for (int dq = 0; dq < 12; ++dq) {
            float4 a4 = *(const float4*)&att[c][dq * 4];
            a0 += a4.x * h0[4 * dq] + a4.y * h0[4 * dq + 1] + a4.z * h0[4 * dq + 2] + a4.w * h0[4 * dq + 3];
            a1 += a4.x * h1[4 * dq] + a4.y * h1[4 * dq + 1] + a4.z * h1[4 * dq + 2] + a4.w * h1[4 * dq + 3];
        }
        out[(size_t)(b * CO + 64 + c) * LL + l] = a0;
        out[(size_t)(b * CO + 64 + c) * LL + l + 256] = a1;
    }
}

extern "C" void kernel_launch(void* const* d_in, const int* in_sizes, int n_in,
                              void* d_out, int out_size, void* d_ws, size_t ws_size,
                              hipStream_t stream) {
    const float* x      = (const float*)d_in[0];
    const float* gamma1 = (const float*)d_in[1];
    const float* beta1  = (const float*)d_in[2];
    const float* W1     = (const float*)d_in[3];
    const float* gamma2 = (const float*)d_in[4];
    const float* beta2  = (const float*)d_in[5];
    const float* W2     = (const float*)d_in[6];
    float* out = (float*)d_out;

    unsigned short* out1 = (unsigned short*)d_ws;
    float* h   = (float*)((char*)d_ws + OUT1_BYTES);
    float* zr  = (float*)((char*)d_ws + OUT1_BYTES + H_BYTES);
    float* par = zr + ZR_FLOATS;
    unsigned short* W1p = (unsigned short*)(par + 512);
    unsigned short* W2p = W1p + PP * C0;

    hipMemsetAsync(zr, 0, (size_t)ZR_FLOATS * sizeof(float), stream);

    const float invN = 1.0f / (float)((size_t)BB * LL);
    kp_pack<<<108, 256, 0, stream>>>(W1, W2, W1p, W2p);
    k1_stats_copy<<<dim3(BB, 4), 256, 0, stream>>>(x, out, zr + ZO_BN1S, zr + ZO_BN1Q);
    k_bn_final<<<1, 64, 0, stream>>>(zr + ZO_BN1S, zr + ZO_BN1Q, gamma1, beta1,
                                     par + 0, par + 64, C0, 8, invN);
    k2_conv1<<<dim3(BB, 16), 256, 0, stream>>>(x, W1p, par, out1, zr + ZO_BN2S, zr + ZO_BN2Q);
    k_bn_final<<<1, 192, 0, stream>>>(zr + ZO_BN2S, zr + ZO_BN2Q, gamma2, beta2,
                                      par + 128, par + 320, PP, 32, invN);
    k4_conv2<<<dim3(BB, 16), 256, 0, stream>>>(out1, W2p, par, h, zr + ZO_NRM);
    k6_gram<<<dim3(BB, 4), 256, 0, stream>>>(h, zr + ZO_SIM);
    k7_softmax_pv<<<dim3(BB, 4), 256, 0, stream>>>(h, zr + ZO_SIM, zr + ZO_NRM, out);
}